// Round 5
// baseline (38479.446 us; speedup 1.0000x reference)
//
#include <hip/hip_runtime.h>
#include <cstdint>
#include <cstddef>

#define SEQ   8192
#define EMB   512
#define HID   2048
#define NCH   256
#define CAT   (EMB + HID)        // 2560
#define NBLK  256                // one block per CU
#define NTH   512                // 8 waves, 2 waves/EU -> 256-reg unified budget
#define NQ    10                 // float4 chunks per lane per gate: 2560/64/4

__device__ __forceinline__ unsigned long long packpair(float v, unsigned tag) {
    return ((unsigned long long)tag << 32) | (unsigned long long)__float_as_uint(v);
}

// Wave sum via DPP row_shr (VALU-only): after 1/2/4/8 the row sums sit in
// lanes 15/31/47/63; two xor-shuffles finish. Valid at lane 63 (proven R4).
#define DPP_ADD(x, ctrl) \
    x += __int_as_float(__builtin_amdgcn_update_dpp(0, __float_as_int(x), ctrl, 0xF, 0xF, true))

__device__ __forceinline__ float wave_sum(float x) {
    DPP_ADD(x, 0x111);
    DPP_ADD(x, 0x112);
    DPP_ADD(x, 0x114);
    DPP_ADD(x, 0x118);
    x += __shfl_xor(x, 16, 64);
    x += __shfl_xor(x, 32, 64);
    return x;            // valid at lanes {15,31,47,63}
}

// Pin into an AGPR: the RA cannot rematerialize or cheaply spill these.
#define AGPR_W(dst, src) \
    asm volatile("v_accvgpr_write_b32 %0, %1" : "=a"(dst) : "v"(src))
// Volatile read: must execute every iteration -> weights stay in AGPRs,
// not hoisted back into (spillable) VGPR copies.
#define AGPR_R(dst, src) \
    asm volatile("v_accvgpr_read_b32 %0, %1" : "=v"(dst) : "a"(src))

__global__
__attribute__((amdgpu_flat_work_group_size(NTH, NTH)))
__attribute__((amdgpu_waves_per_eu(2, 2)))
void lstm_persistent(const int* __restrict__ seq,
                     const float* __restrict__ h0,
                     const float* __restrict__ c0,
                     const float* __restrict__ emb,
                     const float* __restrict__ Wf, const float* __restrict__ bfv,
                     const float* __restrict__ Wi, const float* __restrict__ biv,
                     const float* __restrict__ Wo, const float* __restrict__ bov,
                     const float* __restrict__ Wc, const float* __restrict__ bcv,
                     const float* __restrict__ Wout, const float* __restrict__ boutv,
                     float* __restrict__ out,
                     unsigned long long* __restrict__ hbuf)   // [2][HID] tagged pairs
{
    const int cu  = blockIdx.x;           // 0..255
    const int tid = threadIdx.x;          // 0..511
    const int wv  = tid >> 6;             // wave 0..7
    const int ln  = tid & 63;
    const int j   = cu * 8 + wv;          // gate-row owned by this wave

    __shared__ float z_lds[CAT];
    __shared__ float wred[8];

    // ---- persistent weights: 160 floats/lane pinned in AGPRs ----
    float a_[4][NQ][4];                   // AGPR-class values (static indexing only)
    #pragma unroll
    for (int g = 0; g < 4; ++g) {
        const float* W = (g == 0) ? Wf : (g == 1) ? Wi : (g == 2) ? Wo : Wc;
        const float* r = W + (size_t)j * CAT + 4 * ln;
        #pragma unroll
        for (int q = 0; q < NQ; ++q) {
            const float4 v = *(const float4*)(r + q * 256);
            AGPR_W(a_[g][q][0], v.x);
            AGPR_W(a_[g][q][1], v.y);
            AGPR_W(a_[g][q][2], v.z);
            AGPR_W(a_[g][q][3], v.w);
        }
    }
    const float4 ww = *(const float4*)(Wout + (size_t)cu * HID + tid * 4);
    const float b0 = bfv[j], b1 = biv[j], b2 = bov[j], b3 = bcv[j];
    const float bout_cu = boutv[cu];

    float c = c0[j];                      // meaningful at lane 63 (the owner)

    if (ln == 63) {
        __hip_atomic_store(&hbuf[j], packpair(h0[j], 1u),
                           __ATOMIC_RELAXED, __HIP_MEMORY_SCOPE_AGENT);
    }

    int budget = 1 << 22;                 // loud-fail spin budget
    float hv0 = 0.f, hv1 = 0.f, hv2 = 0.f, hv3 = 0.f;

    for (int t = 0; t < SEQ; ++t) {
        // issue x_t load early (overlaps the poll)
        float4 xv;
        if (tid < EMB / 4) {
            xv = *(const float4*)(emb + (size_t)seq[t] * EMB + tid * 4);
        }

        // poll own 4 components of h_t (tag t+1) in slot t&1
        {
            unsigned long long* p = hbuf + (size_t)(t & 1) * HID + tid * 4;
            const unsigned want = (unsigned)(t + 1);
            unsigned long long v0, v1, v2, v3;
            while (true) {
                v0 = __hip_atomic_load(p + 0, __ATOMIC_RELAXED, __HIP_MEMORY_SCOPE_AGENT);
                v1 = __hip_atomic_load(p + 1, __ATOMIC_RELAXED, __HIP_MEMORY_SCOPE_AGENT);
                v2 = __hip_atomic_load(p + 2, __ATOMIC_RELAXED, __HIP_MEMORY_SCOPE_AGENT);
                v3 = __hip_atomic_load(p + 3, __ATOMIC_RELAXED, __HIP_MEMORY_SCOPE_AGENT);
                if ((unsigned)(v0 >> 32) == want && (unsigned)(v1 >> 32) == want &&
                    (unsigned)(v2 >> 32) == want && (unsigned)(v3 >> 32) == want) break;
                if (--budget < 0) break;
                __builtin_amdgcn_s_sleep(1);
            }
            hv0 = __uint_as_float((unsigned)v0);
            hv1 = __uint_as_float((unsigned)v1);
            hv2 = __uint_as_float((unsigned)v2);
            hv3 = __uint_as_float((unsigned)v3);
        }
        if (tid < EMB / 4) *(float4*)&z_lds[tid * 4] = xv;
        *(float4*)&z_lds[EMB + tid * 4] = make_float4(hv0, hv1, hv2, hv3);
        __syncthreads();

        // 4 gate dots over full CAT; weights re-read from AGPRs each step
        float ac0 = 0.f, ac1 = 0.f, ac2 = 0.f, ac3 = 0.f;
        #pragma unroll
        for (int q = 0; q < NQ; ++q) {
            const float4 zv = *(const float4*)&z_lds[q * 256 + 4 * ln];
            float t0, t1, t2, t3;
            AGPR_R(t0, a_[0][q][0]); AGPR_R(t1, a_[0][q][1]);
            AGPR_R(t2, a_[0][q][2]); AGPR_R(t3, a_[0][q][3]);
            ac0 = fmaf(t0, zv.x, ac0); ac0 = fmaf(t1, zv.y, ac0);
            ac0 = fmaf(t2, zv.z, ac0); ac0 = fmaf(t3, zv.w, ac0);
            AGPR_R(t0, a_[1][q][0]); AGPR_R(t1, a_[1][q][1]);
            AGPR_R(t2, a_[1][q][2]); AGPR_R(t3, a_[1][q][3]);
            ac1 = fmaf(t0, zv.x, ac1); ac1 = fmaf(t1, zv.y, ac1);
            ac1 = fmaf(t2, zv.z, ac1); ac1 = fmaf(t3, zv.w, ac1);
            AGPR_R(t0, a_[2][q][0]); AGPR_R(t1, a_[2][q][1]);
            AGPR_R(t2, a_[2][q][2]); AGPR_R(t3, a_[2][q][3]);
            ac2 = fmaf(t0, zv.x, ac2); ac2 = fmaf(t1, zv.y, ac2);
            ac2 = fmaf(t2, zv.z, ac2); ac2 = fmaf(t3, zv.w, ac2);
            AGPR_R(t0, a_[3][q][0]); AGPR_R(t1, a_[3][q][1]);
            AGPR_R(t2, a_[3][q][2]); AGPR_R(t3, a_[3][q][3]);
            ac3 = fmaf(t0, zv.x, ac3); ac3 = fmaf(t1, zv.y, ac3);
            ac3 = fmaf(t2, zv.z, ac3); ac3 = fmaf(t3, zv.w, ac3);
        }
        // Wout partial for pred_{t-1} = Wout @ h_t
        float aw = fmaf(ww.x, hv0, fmaf(ww.y, hv1, fmaf(ww.z, hv2, ww.w * hv3)));

        ac0 = wave_sum(ac0); ac1 = wave_sum(ac1);
        ac2 = wave_sum(ac2); ac3 = wave_sum(ac3);
        aw  = wave_sum(aw);

        if (ln == 63) {
            const float gf = 1.f / (1.f + __expf(-(ac0 + b0)));
            const float gi = 1.f / (1.f + __expf(-(ac1 + b1)));
            const float go = 1.f / (1.f + __expf(-(ac2 + b2)));
            const float ct = tanhf(ac3 + b3);
            c = fmaf(gf, c, gi * ct);
            const float hn = go * tanhf(c);
            // publish first: inter-CU critical path
            __hip_atomic_store(&hbuf[(size_t)((t + 1) & 1) * HID + j],
                               packpair(hn, (unsigned)(t + 2)),
                               __ATOMIC_RELAXED, __HIP_MEMORY_SCOPE_AGENT);
            wred[wv] = aw;
        }
        __syncthreads();
        if (tid == NTH - 1 && t >= 1) {
            float s = bout_cu;
            #pragma unroll
            for (int q = 0; q < 8; ++q) s += wred[q];
            out[(size_t)(t - 1) * NCH + cu] = s;
        }
    }

    // ---- epilogue: pred_{SEQ-1} = Wout @ h_SEQ (tag SEQ+1, slot 0) ----
    {
        unsigned long long* p = hbuf + (size_t)(SEQ & 1) * HID + tid * 4;
        const unsigned want = (unsigned)(SEQ + 1);
        unsigned long long v0, v1, v2, v3;
        while (true) {
            v0 = __hip_atomic_load(p + 0, __ATOMIC_RELAXED, __HIP_MEMORY_SCOPE_AGENT);
            v1 = __hip_atomic_load(p + 1, __ATOMIC_RELAXED, __HIP_MEMORY_SCOPE_AGENT);
            v2 = __hip_atomic_load(p + 2, __ATOMIC_RELAXED, __HIP_MEMORY_SCOPE_AGENT);
            v3 = __hip_atomic_load(p + 3, __ATOMIC_RELAXED, __HIP_MEMORY_SCOPE_AGENT);
            if ((unsigned)(v0 >> 32) == want && (unsigned)(v1 >> 32) == want &&
                (unsigned)(v2 >> 32) == want && (unsigned)(v3 >> 32) == want) break;
            if (--budget < 0) break;
            __builtin_amdgcn_s_sleep(1);
        }
        hv0 = __uint_as_float((unsigned)v0);
        hv1 = __uint_as_float((unsigned)v1);
        hv2 = __uint_as_float((unsigned)v2);
        hv3 = __uint_as_float((unsigned)v3);

        float aw = fmaf(ww.x, hv0, fmaf(ww.y, hv1, fmaf(ww.z, hv2, ww.w * hv3)));
        aw = wave_sum(aw);
        if (ln == 63) wred[wv] = aw;
        __syncthreads();
        if (tid == NTH - 1) {
            float s = bout_cu;
            #pragma unroll
            for (int q = 0; q < 8; ++q) s += wred[q];
            out[(size_t)(SEQ - 1) * NCH + cu] = s;
        }
        // final hidden state
        if (cu == 0) {
            *(float4*)&out[(size_t)SEQ * NCH + tid * 4] =
                make_float4(hv0, hv1, hv2, hv3);
        }
        // final cell state
        if (ln == 63) out[(size_t)SEQ * NCH + HID + j] = c;
    }
}

extern "C" void kernel_launch(void* const* d_in, const int* in_sizes, int n_in,
                              void* d_out, int out_size, void* d_ws, size_t ws_size,
                              hipStream_t stream)
{
    const int*   seq  = (const int*)  d_in[0];
    const float* h0   = (const float*)d_in[1];
    const float* c0   = (const float*)d_in[2];
    const float* emb  = (const float*)d_in[3];
    const float* Wf   = (const float*)d_in[4];
    const float* bf_  = (const float*)d_in[5];
    const float* Wi   = (const float*)d_in[6];
    const float* bi_  = (const float*)d_in[7];
    const float* Wo   = (const float*)d_in[8];
    const float* bo_  = (const float*)d_in[9];
    const float* Wc   = (const float*)d_in[10];
    const float* bc_  = (const float*)d_in[11];
    const float* Wout = (const float*)d_in[12];
    const float* bout = (const float*)d_in[13];
    float* out = (float*)d_out;
    unsigned long long* hbuf = (unsigned long long*)d_ws;  // 32 KB used

    void* args[] = { (void*)&seq, (void*)&h0, (void*)&c0, (void*)&emb,
                     (void*)&Wf, (void*)&bf_, (void*)&Wi, (void*)&bi_,
                     (void*)&Wo, (void*)&bo_, (void*)&Wc, (void*)&bc_,
                     (void*)&Wout, (void*)&bout, (void*)&out, (void*)&hbuf };

    hipError_t e = hipLaunchCooperativeKernel((void*)lstm_persistent,
                                              dim3(NBLK), dim3(NTH),
                                              args, 0, stream);
    if (e != hipSuccess) {
        lstm_persistent<<<dim3(NBLK), dim3(NTH), 0, stream>>>(
            seq, h0, c0, emb, Wf, bf_, Wi, bi_, Wo, bo_, Wc, bc_, Wout, bout,
            out, hbuf);
    }
}

// Round 6
// 33229.886 us; speedup vs baseline: 1.1580x; 1.1580x over previous
//
#include <hip/hip_runtime.h>
#include <cstdint>
#include <cstddef>

#define SEQ   8192
#define EMB   512
#define HID   2048
#define NCH   256
#define CAT   (EMB + HID)        // 2560
#define NBLK  256                // one block per CU
#define NTH   512                // 8 waves, 2 waves/EU
#define NROW  8192               // 2048 j * 4 gates

__device__ __forceinline__ unsigned long long packpair(float v, unsigned tag) {
    return ((unsigned long long)tag << 32) | (unsigned long long)__float_as_uint(v);
}

// Wave sum via DPP row_shr: after 1/2/4/8 the row sums sit in lanes
// 15/31/47/63; two xor-shuffles finish. Valid at lane 63 (proven R4).
#define DPP_ADD(x, ctrl) \
    x += __int_as_float(__builtin_amdgcn_update_dpp(0, __float_as_int(x), ctrl, 0xF, 0xF, true))

__device__ __forceinline__ float wave_sum(float x) {
    DPP_ADD(x, 0x111);
    DPP_ADD(x, 0x112);
    DPP_ADD(x, 0x114);
    DPP_ADD(x, 0x118);
    x += __shfl_xor(x, 16, 64);
    x += __shfl_xor(x, 32, 64);
    return x;            // valid at lanes {15,31,47,63}
}

// ---- weights pinned in HARD-CODED AGPRs a0..a127 (RA can't touch them) ----
#define ST4(N0,N1,N2,N3, V) asm volatile( \
    "v_accvgpr_write_b32 a" #N0 ", %0\n\t" \
    "v_accvgpr_write_b32 a" #N1 ", %1\n\t" \
    "v_accvgpr_write_b32 a" #N2 ", %2\n\t" \
    "v_accvgpr_write_b32 a" #N3 ", %3" \
    :: "v"((V).x), "v"((V).y), "v"((V).z), "v"((V).w) \
    : "a" #N0, "a" #N1, "a" #N2, "a" #N3)

// One K-chunk (4 floats) for all 4 gates: 16 accvgpr_read + 16 fmac,
// interleaved for ILP. t-regs v68-71, z in Z0..Z3 (hard reg names).
#define DOT16(A0,A1,A2,A3, B0,B1,B2,B3, C0,C1,C2,C3, D0,D1,D2,D3, Z0,Z1,Z2,Z3) \
    "v_accvgpr_read_b32 v68, a" #A0 "\n\t" \
    "v_accvgpr_read_b32 v69, a" #B0 "\n\t" \
    "v_accvgpr_read_b32 v70, a" #C0 "\n\t" \
    "v_accvgpr_read_b32 v71, a" #D0 "\n\t" \
    "v_fmac_f32 %0, v68, " Z0 "\n\t" \
    "v_accvgpr_read_b32 v68, a" #A1 "\n\t" \
    "v_fmac_f32 %1, v69, " Z0 "\n\t" \
    "v_accvgpr_read_b32 v69, a" #B1 "\n\t" \
    "v_fmac_f32 %2, v70, " Z0 "\n\t" \
    "v_accvgpr_read_b32 v70, a" #C1 "\n\t" \
    "v_fmac_f32 %3, v71, " Z0 "\n\t" \
    "v_accvgpr_read_b32 v71, a" #D1 "\n\t" \
    "v_fmac_f32 %0, v68, " Z1 "\n\t" \
    "v_accvgpr_read_b32 v68, a" #A2 "\n\t" \
    "v_fmac_f32 %1, v69, " Z1 "\n\t" \
    "v_accvgpr_read_b32 v69, a" #B2 "\n\t" \
    "v_fmac_f32 %2, v70, " Z1 "\n\t" \
    "v_accvgpr_read_b32 v70, a" #C2 "\n\t" \
    "v_fmac_f32 %3, v71, " Z1 "\n\t" \
    "v_accvgpr_read_b32 v71, a" #D2 "\n\t" \
    "v_fmac_f32 %0, v68, " Z2 "\n\t" \
    "v_accvgpr_read_b32 v68, a" #A3 "\n\t" \
    "v_fmac_f32 %1, v69, " Z2 "\n\t" \
    "v_accvgpr_read_b32 v69, a" #B3 "\n\t" \
    "v_fmac_f32 %2, v70, " Z2 "\n\t" \
    "v_accvgpr_read_b32 v70, a" #C3 "\n\t" \
    "v_fmac_f32 %3, v71, " Z2 "\n\t" \
    "v_accvgpr_read_b32 v71, a" #D3 "\n\t" \
    "v_fmac_f32 %0, v68, " Z3 "\n\t" \
    "v_fmac_f32 %1, v69, " Z3 "\n\t" \
    "v_fmac_f32 %2, v70, " Z3 "\n\t" \
    "v_fmac_f32 %3, v71, " Z3 "\n\t"

#define ACLOB \
    "a0","a1","a2","a3","a4","a5","a6","a7","a8","a9", \
    "a10","a11","a12","a13","a14","a15","a16","a17","a18","a19", \
    "a20","a21","a22","a23","a24","a25","a26","a27","a28","a29", \
    "a30","a31","a32","a33","a34","a35","a36","a37","a38","a39", \
    "a40","a41","a42","a43","a44","a45","a46","a47","a48","a49", \
    "a50","a51","a52","a53","a54","a55","a56","a57","a58","a59", \
    "a60","a61","a62","a63","a64","a65","a66","a67","a68","a69", \
    "a70","a71","a72","a73","a74","a75","a76","a77","a78","a79", \
    "a80","a81","a82","a83","a84","a85","a86","a87","a88","a89", \
    "a90","a91","a92","a93","a94","a95","a96","a97","a98","a99", \
    "a100","a101","a102","a103","a104","a105","a106","a107","a108","a109", \
    "a110","a111","a112","a113","a114","a115","a116","a117","a118","a119", \
    "a120","a121","a122","a123","a124","a125","a126","a127"
#define VCLOB \
    "v60","v61","v62","v63","v64","v65","v66","v67","v68","v69","v70","v71"

// ---------- pass 1: per-character x-contribution table ----------
// P[ch][j*4+g] = W_g[j, 0:512] . emb[ch] + b_g[j]
__global__ __launch_bounds__(256)
void build_ptab(const float* __restrict__ emb,
                const float* __restrict__ Wf, const float* __restrict__ Wi,
                const float* __restrict__ Wo, const float* __restrict__ Wc,
                const float* __restrict__ bfv, const float* __restrict__ biv,
                const float* __restrict__ bov, const float* __restrict__ bcv,
                float* __restrict__ P)
{
    const int r = blockIdx.x;            // row = j*4 + g, 0..8191
    const int j = r >> 2, g = r & 3;
    const float* W = (g == 0 ? Wf : g == 1 ? Wi : g == 2 ? Wo : Wc) + (size_t)j * CAT;
    const float  b = (g == 0 ? bfv : g == 1 ? biv : g == 2 ? bov : bcv)[j];
    const float* x = emb + (size_t)threadIdx.x * EMB;
    float acc = 0.f;
    #pragma unroll 8
    for (int k = 0; k < EMB; k += 4) {
        const float4 w4 = *(const float4*)(W + k);   // wave-uniform (broadcast)
        const float4 x4 = *(const float4*)(x + k);
        acc = fmaf(w4.x, x4.x, acc); acc = fmaf(w4.y, x4.y, acc);
        acc = fmaf(w4.z, x4.z, acc); acc = fmaf(w4.w, x4.w, acc);
    }
    P[((size_t)threadIdx.x << 13) + r] = acc + b;
}

// ---------- pass 2: persistent recurrence ----------
__global__
__attribute__((amdgpu_flat_work_group_size(NTH, NTH)))
__attribute__((amdgpu_waves_per_eu(2, 2)))
void lstm_persistent(const int* __restrict__ seq,
                     const float* __restrict__ h0,
                     const float* __restrict__ c0,
                     const float* __restrict__ Wf, const float* __restrict__ Wi,
                     const float* __restrict__ Wo, const float* __restrict__ Wc,
                     const float* __restrict__ Wout, const float* __restrict__ boutv,
                     const float* __restrict__ Ptab,
                     float* __restrict__ out,
                     unsigned long long* __restrict__ hbuf)
{
    const int cu  = blockIdx.x;           // 0..255
    const int tid = threadIdx.x;          // 0..511
    const int wv  = tid >> 6;             // wave 0..7
    const int ln  = tid & 63;
    const int j   = cu * 8 + wv;          // hidden row owned by this wave

    __shared__ float z_lds[HID];
    __shared__ float wred[8];

    // ---- load W_h (cols 512:2560) into hard AGPRs: a[g*32 + q*4 + i] ----
    {
        const float* r0 = Wf + (size_t)j * CAT + EMB + 4 * ln;
        const float* r1 = Wi + (size_t)j * CAT + EMB + 4 * ln;
        const float* r2 = Wo + (size_t)j * CAT + EMB + 4 * ln;
        const float* r3 = Wc + (size_t)j * CAT + EMB + 4 * ln;
        float4 v;
        v = *(const float4*)(r0 +    0); ST4(0,1,2,3, v);
        v = *(const float4*)(r0 +  256); ST4(4,5,6,7, v);
        v = *(const float4*)(r0 +  512); ST4(8,9,10,11, v);
        v = *(const float4*)(r0 +  768); ST4(12,13,14,15, v);
        v = *(const float4*)(r0 + 1024); ST4(16,17,18,19, v);
        v = *(const float4*)(r0 + 1280); ST4(20,21,22,23, v);
        v = *(const float4*)(r0 + 1536); ST4(24,25,26,27, v);
        v = *(const float4*)(r0 + 1792); ST4(28,29,30,31, v);
        v = *(const float4*)(r1 +    0); ST4(32,33,34,35, v);
        v = *(const float4*)(r1 +  256); ST4(36,37,38,39, v);
        v = *(const float4*)(r1 +  512); ST4(40,41,42,43, v);
        v = *(const float4*)(r1 +  768); ST4(44,45,46,47, v);
        v = *(const float4*)(r1 + 1024); ST4(48,49,50,51, v);
        v = *(const float4*)(r1 + 1280); ST4(52,53,54,55, v);
        v = *(const float4*)(r1 + 1536); ST4(56,57,58,59, v);
        v = *(const float4*)(r1 + 1792); ST4(60,61,62,63, v);
        v = *(const float4*)(r2 +    0); ST4(64,65,66,67, v);
        v = *(const float4*)(r2 +  256); ST4(68,69,70,71, v);
        v = *(const float4*)(r2 +  512); ST4(72,73,74,75, v);
        v = *(const float4*)(r2 +  768); ST4(76,77,78,79, v);
        v = *(const float4*)(r2 + 1024); ST4(80,81,82,83, v);
        v = *(const float4*)(r2 + 1280); ST4(84,85,86,87, v);
        v = *(const float4*)(r2 + 1536); ST4(88,89,90,91, v);
        v = *(const float4*)(r2 + 1792); ST4(92,93,94,95, v);
        v = *(const float4*)(r3 +    0); ST4(96,97,98,99, v);
        v = *(const float4*)(r3 +  256); ST4(100,101,102,103, v);
        v = *(const float4*)(r3 +  512); ST4(104,105,106,107, v);
        v = *(const float4*)(r3 +  768); ST4(108,109,110,111, v);
        v = *(const float4*)(r3 + 1024); ST4(112,113,114,115, v);
        v = *(const float4*)(r3 + 1280); ST4(116,117,118,119, v);
        v = *(const float4*)(r3 + 1536); ST4(120,121,122,123, v);
        v = *(const float4*)(r3 + 1792); ST4(124,125,126,127, v);
    }
    const float4 ww = *(const float4*)(Wout + (size_t)cu * HID + tid * 4);
    const float bout_cu = boutv[cu];
    const unsigned zaddr = (unsigned)(size_t)&z_lds[4 * ln];   // LDS byte offset

    float c = c0[j];                      // meaningful at lane 63 (the owner)
    if (ln == 63) {
        __hip_atomic_store(&hbuf[j], packpair(h0[j], 1u),
                           __ATOMIC_RELAXED, __HIP_MEMORY_SCOPE_AGENT);
    }

    int budget = 1 << 22;                 // loud-fail spin budget
    float hv0 = 0.f, hv1 = 0.f, hv2 = 0.f, hv3 = 0.f;
    int ch = seq[0];

    #pragma unroll 1
    for (int t = 0; t < SEQ; ++t) {
        // x-contribution for this step: one broadcast float4 (issue early).
        int chv = ch;
        asm volatile("" : "+v"(chv));     // launder -> VMEM path (vmcnt)
        const float4 p4 = *(const float4*)(Ptab + ((size_t)(unsigned)chv << 13) + (j << 2));
        if (t + 1 < SEQ) ch = seq[t + 1]; // prefetch next char (scalar, off-path)

        // poll own 4 components of h_t (tag t+1) in slot t&1
        {
            unsigned long long* p = hbuf + (size_t)(t & 1) * HID + tid * 4;
            const unsigned want = (unsigned)(t + 1);
            unsigned long long v0, v1, v2, v3;
            while (true) {
                v0 = __hip_atomic_load(p + 0, __ATOMIC_RELAXED, __HIP_MEMORY_SCOPE_AGENT);
                v1 = __hip_atomic_load(p + 1, __ATOMIC_RELAXED, __HIP_MEMORY_SCOPE_AGENT);
                v2 = __hip_atomic_load(p + 2, __ATOMIC_RELAXED, __HIP_MEMORY_SCOPE_AGENT);
                v3 = __hip_atomic_load(p + 3, __ATOMIC_RELAXED, __HIP_MEMORY_SCOPE_AGENT);
                if ((unsigned)(v0 >> 32) == want && (unsigned)(v1 >> 32) == want &&
                    (unsigned)(v2 >> 32) == want && (unsigned)(v3 >> 32) == want) break;
                if (--budget < 0) break;
                __builtin_amdgcn_s_sleep(1);
            }
            hv0 = __uint_as_float((unsigned)v0);
            hv1 = __uint_as_float((unsigned)v1);
            hv2 = __uint_as_float((unsigned)v2);
            hv3 = __uint_as_float((unsigned)v3);
        }
        *(float4*)&z_lds[tid * 4] = make_float4(hv0, hv1, hv2, hv3);
        __syncthreads();

        // 4 gate dots over h (K=2048): one opaque asm block, weights from AGPRs
        float ac0 = 0.f, ac1 = 0.f, ac2 = 0.f, ac3 = 0.f;
        asm volatile(
            "s_waitcnt lgkmcnt(0)\n\t"
            "ds_read_b128 v[60:63], %[za] offset:0\n\t"
            "ds_read_b128 v[64:67], %[za] offset:1024\n\t"
            "s_waitcnt lgkmcnt(1)\n\t"
            DOT16(0,1,2,3, 32,33,34,35, 64,65,66,67, 96,97,98,99, "v60","v61","v62","v63")
            "ds_read_b128 v[60:63], %[za] offset:2048\n\t"
            "s_waitcnt lgkmcnt(1)\n\t"
            DOT16(4,5,6,7, 36,37,38,39, 68,69,70,71, 100,101,102,103, "v64","v65","v66","v67")
            "ds_read_b128 v[64:67], %[za] offset:3072\n\t"
            "s_waitcnt lgkmcnt(1)\n\t"
            DOT16(8,9,10,11, 40,41,42,43, 72,73,74,75, 104,105,106,107, "v60","v61","v62","v63")
            "ds_read_b128 v[60:63], %[za] offset:4096\n\t"
            "s_waitcnt lgkmcnt(1)\n\t"
            DOT16(12,13,14,15, 44,45,46,47, 76,77,78,79, 108,109,110,111, "v64","v65","v66","v67")
            "ds_read_b128 v[64:67], %[za] offset:5120\n\t"
            "s_waitcnt lgkmcnt(1)\n\t"
            DOT16(16,17,18,19, 48,49,50,51, 80,81,82,83, 112,113,114,115, "v60","v61","v62","v63")
            "ds_read_b128 v[60:63], %[za] offset:6144\n\t"
            "s_waitcnt lgkmcnt(1)\n\t"
            DOT16(20,21,22,23, 52,53,54,55, 84,85,86,87, 116,117,118,119, "v64","v65","v66","v67")
            "ds_read_b128 v[64:67], %[za] offset:7168\n\t"
            "s_waitcnt lgkmcnt(1)\n\t"
            DOT16(24,25,26,27, 56,57,58,59, 88,89,90,91, 120,121,122,123, "v60","v61","v62","v63")
            "s_waitcnt lgkmcnt(0)\n\t"
            DOT16(28,29,30,31, 60,61,62,63, 92,93,94,95, 124,125,126,127, "v64","v65","v66","v67")
            : "+v"(ac0), "+v"(ac1), "+v"(ac2), "+v"(ac3)
            : [za] "v"(zaddr)
            : ACLOB, VCLOB, "memory");

        // Wout partial for pred_{t-1} = Wout @ h_t
        float aw = fmaf(ww.x, hv0, fmaf(ww.y, hv1, fmaf(ww.z, hv2, ww.w * hv3)));

        ac0 = wave_sum(ac0); ac1 = wave_sum(ac1);
        ac2 = wave_sum(ac2); ac3 = wave_sum(ac3);
        aw  = wave_sum(aw);

        if (ln == 63) {
            const float gf = 1.f / (1.f + __expf(-(ac0 + p4.x)));
            const float gi = 1.f / (1.f + __expf(-(ac1 + p4.y)));
            const float go = 1.f / (1.f + __expf(-(ac2 + p4.z)));
            const float ct = tanhf(ac3 + p4.w);
            c = fmaf(gf, c, gi * ct);
            const float hn = go * tanhf(c);
            __hip_atomic_store(&hbuf[(size_t)((t + 1) & 1) * HID + j],
                               packpair(hn, (unsigned)(t + 2)),
                               __ATOMIC_RELAXED, __HIP_MEMORY_SCOPE_AGENT);
            wred[wv] = aw;
        }
        __syncthreads();
        if (tid == NTH - 1 && t >= 1) {
            float s = bout_cu;
            #pragma unroll
            for (int q = 0; q < 8; ++q) s += wred[q];
            out[(size_t)(t - 1) * NCH + cu] = s;
        }
    }

    // ---- epilogue: pred_{SEQ-1} = Wout @ h_SEQ (tag SEQ+1, slot 0) ----
    {
        unsigned long long* p = hbuf + (size_t)(SEQ & 1) * HID + tid * 4;
        const unsigned want = (unsigned)(SEQ + 1);
        unsigned long long v0, v1, v2, v3;
        while (true) {
            v0 = __hip_atomic_load(p + 0, __ATOMIC_RELAXED, __HIP_MEMORY_SCOPE_AGENT);
            v1 = __hip_atomic_load(p + 1, __ATOMIC_RELAXED, __HIP_MEMORY_SCOPE_AGENT);
            v2 = __hip_atomic_load(p + 2, __ATOMIC_RELAXED, __HIP_MEMORY_SCOPE_AGENT);
            v3 = __hip_atomic_load(p + 3, __ATOMIC_RELAXED, __HIP_MEMORY_SCOPE_AGENT);
            if ((unsigned)(v0 >> 32) == want && (unsigned)(v1 >> 32) == want &&
                (unsigned)(v2 >> 32) == want && (unsigned)(v3 >> 32) == want) break;
            if (--budget < 0) break;
            __builtin_amdgcn_s_sleep(1);
        }
        hv0 = __uint_as_float((unsigned)v0);
        hv1 = __uint_as_float((unsigned)v1);
        hv2 = __uint_as_float((unsigned)v2);
        hv3 = __uint_as_float((unsigned)v3);

        float aw = fmaf(ww.x, hv0, fmaf(ww.y, hv1, fmaf(ww.z, hv2, ww.w * hv3)));
        aw = wave_sum(aw);
        if (ln == 63) wred[wv] = aw;
        __syncthreads();
        if (tid == NTH - 1) {
            float s = bout_cu;
            #pragma unroll
            for (int q = 0; q < 8; ++q) s += wred[q];
            out[(size_t)(SEQ - 1) * NCH + cu] = s;
        }
        if (cu == 0) {
            *(float4*)&out[(size_t)SEQ * NCH + tid * 4] =
                make_float4(hv0, hv1, hv2, hv3);
        }
        if (ln == 63) out[(size_t)SEQ * NCH + HID + j] = c;
    }
}

extern "C" void kernel_launch(void* const* d_in, const int* in_sizes, int n_in,
                              void* d_out, int out_size, void* d_ws, size_t ws_size,
                              hipStream_t stream)
{
    const int*   seq  = (const int*)  d_in[0];
    const float* h0   = (const float*)d_in[1];
    const float* c0   = (const float*)d_in[2];
    const float* emb  = (const float*)d_in[3];
    const float* Wf   = (const float*)d_in[4];
    const float* bf_  = (const float*)d_in[5];
    const float* Wi   = (const float*)d_in[6];
    const float* bi_  = (const float*)d_in[7];
    const float* Wo   = (const float*)d_in[8];
    const float* bo_  = (const float*)d_in[9];
    const float* Wc   = (const float*)d_in[10];
    const float* bc_  = (const float*)d_in[11];
    const float* Wout = (const float*)d_in[12];
    const float* bout = (const float*)d_in[13];
    float* out = (float*)d_out;

    unsigned long long* hbuf = (unsigned long long*)d_ws;        // 32 KB
    float* Ptab = (float*)((char*)d_ws + 2 * HID * sizeof(unsigned long long)); // 8 MB

    build_ptab<<<dim3(NROW), dim3(256), 0, stream>>>(
        emb, Wf, Wi, Wo, Wc, bf_, bi_, bo_, bc_, Ptab);

    void* args[] = { (void*)&seq, (void*)&h0, (void*)&c0,
                     (void*)&Wf, (void*)&Wi, (void*)&Wo, (void*)&Wc,
                     (void*)&Wout, (void*)&bout, (void*)&Ptab,
                     (void*)&out, (void*)&hbuf };

    hipError_t e = hipLaunchCooperativeKernel((void*)lstm_persistent,
                                              dim3(NBLK), dim3(NTH),
                                              args, 0, stream);
    if (e != hipSuccess) {
        lstm_persistent<<<dim3(NBLK), dim3(NTH), 0, stream>>>(
            seq, h0, c0, Wf, Wi, Wo, Wc, Wout, bout, Ptab, out, hbuf);
    }
}

// Round 7
// 22793.973 us; speedup vs baseline: 1.6881x; 1.4578x over previous
//
#include <hip/hip_runtime.h>
#include <cstdint>
#include <cstddef>

#define SEQ   8192
#define EMB   512
#define HID   2048
#define NCH   256
#define CAT   (EMB + HID)        // 2560
#define NBLK  256                // one block per CU
#define NTH   512                // 8 waves, 2 waves/EU
#define NROW  8192               // 2048 j * 4 gates

typedef unsigned int u32x4 __attribute__((ext_vector_type(4)));

__device__ __forceinline__ unsigned long long packpair(float v, unsigned tag) {
    return ((unsigned long long)tag << 32) | (unsigned long long)__float_as_uint(v);
}

// Wave sum via DPP row_shr: after 1/2/4/8 the row sums sit in lanes
// 15/31/47/63; two xor-shuffles finish. Valid at lane 63 (proven R4).
#define DPP_ADD(x, ctrl) \
    x += __int_as_float(__builtin_amdgcn_update_dpp(0, __float_as_int(x), ctrl, 0xF, 0xF, true))

__device__ __forceinline__ float wave_sum(float x) {
    DPP_ADD(x, 0x111);
    DPP_ADD(x, 0x112);
    DPP_ADD(x, 0x114);
    DPP_ADD(x, 0x118);
    x += __shfl_xor(x, 16, 64);
    x += __shfl_xor(x, 32, 64);
    return x;            // valid at lanes {15,31,47,63}
}

// ---- weights pinned in HARD-CODED AGPRs a0..a127 (RA can't touch them) ----
#define ST4(N0,N1,N2,N3, V) asm volatile( \
    "v_accvgpr_write_b32 a" #N0 ", %0\n\t" \
    "v_accvgpr_write_b32 a" #N1 ", %1\n\t" \
    "v_accvgpr_write_b32 a" #N2 ", %2\n\t" \
    "v_accvgpr_write_b32 a" #N3 ", %3" \
    :: "v"((V).x), "v"((V).y), "v"((V).z), "v"((V).w) \
    : "a" #N0, "a" #N1, "a" #N2, "a" #N3)

#define DOT16(A0,A1,A2,A3, B0,B1,B2,B3, C0,C1,C2,C3, D0,D1,D2,D3, Z0,Z1,Z2,Z3) \
    "v_accvgpr_read_b32 v68, a" #A0 "\n\t" \
    "v_accvgpr_read_b32 v69, a" #B0 "\n\t" \
    "v_accvgpr_read_b32 v70, a" #C0 "\n\t" \
    "v_accvgpr_read_b32 v71, a" #D0 "\n\t" \
    "v_fmac_f32 %0, v68, " Z0 "\n\t" \
    "v_accvgpr_read_b32 v68, a" #A1 "\n\t" \
    "v_fmac_f32 %1, v69, " Z0 "\n\t" \
    "v_accvgpr_read_b32 v69, a" #B1 "\n\t" \
    "v_fmac_f32 %2, v70, " Z0 "\n\t" \
    "v_accvgpr_read_b32 v70, a" #C1 "\n\t" \
    "v_fmac_f32 %3, v71, " Z0 "\n\t" \
    "v_accvgpr_read_b32 v71, a" #D1 "\n\t" \
    "v_fmac_f32 %0, v68, " Z1 "\n\t" \
    "v_accvgpr_read_b32 v68, a" #A2 "\n\t" \
    "v_fmac_f32 %1, v69, " Z1 "\n\t" \
    "v_accvgpr_read_b32 v69, a" #B2 "\n\t" \
    "v_fmac_f32 %2, v70, " Z1 "\n\t" \
    "v_accvgpr_read_b32 v70, a" #C2 "\n\t" \
    "v_fmac_f32 %3, v71, " Z1 "\n\t" \
    "v_accvgpr_read_b32 v71, a" #D2 "\n\t" \
    "v_fmac_f32 %0, v68, " Z2 "\n\t" \
    "v_accvgpr_read_b32 v68, a" #A3 "\n\t" \
    "v_fmac_f32 %1, v69, " Z2 "\n\t" \
    "v_accvgpr_read_b32 v69, a" #B3 "\n\t" \
    "v_fmac_f32 %2, v70, " Z2 "\n\t" \
    "v_accvgpr_read_b32 v70, a" #C3 "\n\t" \
    "v_fmac_f32 %3, v71, " Z2 "\n\t" \
    "v_accvgpr_read_b32 v71, a" #D3 "\n\t" \
    "v_fmac_f32 %0, v68, " Z3 "\n\t" \
    "v_fmac_f32 %1, v69, " Z3 "\n\t" \
    "v_fmac_f32 %2, v70, " Z3 "\n\t" \
    "v_fmac_f32 %3, v71, " Z3 "\n\t"

#define ACLOB \
    "a0","a1","a2","a3","a4","a5","a6","a7","a8","a9", \
    "a10","a11","a12","a13","a14","a15","a16","a17","a18","a19", \
    "a20","a21","a22","a23","a24","a25","a26","a27","a28","a29", \
    "a30","a31","a32","a33","a34","a35","a36","a37","a38","a39", \
    "a40","a41","a42","a43","a44","a45","a46","a47","a48","a49", \
    "a50","a51","a52","a53","a54","a55","a56","a57","a58","a59", \
    "a60","a61","a62","a63","a64","a65","a66","a67","a68","a69", \
    "a70","a71","a72","a73","a74","a75","a76","a77","a78","a79", \
    "a80","a81","a82","a83","a84","a85","a86","a87","a88","a89", \
    "a90","a91","a92","a93","a94","a95","a96","a97","a98","a99", \
    "a100","a101","a102","a103","a104","a105","a106","a107","a108","a109", \
    "a110","a111","a112","a113","a114","a115","a116","a117","a118","a119", \
    "a120","a121","a122","a123","a124","a125","a126","a127"
#define VCLOB \
    "v60","v61","v62","v63","v64","v65","v66","v67","v68","v69","v70","v71"

// ---------- pass 1: per-character x-contribution table ----------
__global__ __launch_bounds__(256)
void build_ptab(const float* __restrict__ emb,
                const float* __restrict__ Wf, const float* __restrict__ Wi,
                const float* __restrict__ Wo, const float* __restrict__ Wc,
                const float* __restrict__ bfv, const float* __restrict__ biv,
                const float* __restrict__ bov, const float* __restrict__ bcv,
                float* __restrict__ P)
{
    const int r = blockIdx.x;            // row = j*4 + g, 0..8191
    const int j = r >> 2, g = r & 3;
    const float* W = (g == 0 ? Wf : g == 1 ? Wi : g == 2 ? Wo : Wc) + (size_t)j * CAT;
    const float  b = (g == 0 ? bfv : g == 1 ? biv : g == 2 ? bov : bcv)[j];
    const float* x = emb + (size_t)threadIdx.x * EMB;
    float acc = 0.f;
    #pragma unroll 8
    for (int k = 0; k < EMB; k += 4) {
        const float4 w4 = *(const float4*)(W + k);   // wave-uniform (broadcast)
        const float4 x4 = *(const float4*)(x + k);
        acc = fmaf(w4.x, x4.x, acc); acc = fmaf(w4.y, x4.y, acc);
        acc = fmaf(w4.z, x4.z, acc); acc = fmaf(w4.w, x4.w, acc);
    }
    P[((size_t)threadIdx.x << 13) + r] = acc + b;
}

// ---------- pass 2: persistent recurrence ----------
__global__
__attribute__((amdgpu_flat_work_group_size(NTH, NTH)))
__attribute__((amdgpu_waves_per_eu(2, 2)))
void lstm_persistent(const int* __restrict__ seq,
                     const float* __restrict__ h0,
                     const float* __restrict__ c0,
                     const float* __restrict__ Wf, const float* __restrict__ Wi,
                     const float* __restrict__ Wo, const float* __restrict__ Wc,
                     const float* __restrict__ Wout, const float* __restrict__ boutv,
                     const float* __restrict__ Ptab,
                     float* __restrict__ out,
                     unsigned long long* __restrict__ hbuf)
{
    const int cu  = blockIdx.x;           // 0..255
    const int tid = threadIdx.x;          // 0..511
    const int wv  = tid >> 6;             // wave 0..7
    const int ln  = tid & 63;
    const int j   = cu * 8 + wv;          // hidden row owned by this wave

    __shared__ float z_lds[HID];
    __shared__ float wred[8];
    __shared__ float hpub[8];

    // ---- load W_h (cols 512:2560) into hard AGPRs ----
    {
        const float* r0 = Wf + (size_t)j * CAT + EMB + 4 * ln;
        const float* r1 = Wi + (size_t)j * CAT + EMB + 4 * ln;
        const float* r2 = Wo + (size_t)j * CAT + EMB + 4 * ln;
        const float* r3 = Wc + (size_t)j * CAT + EMB + 4 * ln;
        float4 v;
        v = *(const float4*)(r0 +    0); ST4(0,1,2,3, v);
        v = *(const float4*)(r0 +  256); ST4(4,5,6,7, v);
        v = *(const float4*)(r0 +  512); ST4(8,9,10,11, v);
        v = *(const float4*)(r0 +  768); ST4(12,13,14,15, v);
        v = *(const float4*)(r0 + 1024); ST4(16,17,18,19, v);
        v = *(const float4*)(r0 + 1280); ST4(20,21,22,23, v);
        v = *(const float4*)(r0 + 1536); ST4(24,25,26,27, v);
        v = *(const float4*)(r0 + 1792); ST4(28,29,30,31, v);
        v = *(const float4*)(r1 +    0); ST4(32,33,34,35, v);
        v = *(const float4*)(r1 +  256); ST4(36,37,38,39, v);
        v = *(const float4*)(r1 +  512); ST4(40,41,42,43, v);
        v = *(const float4*)(r1 +  768); ST4(44,45,46,47, v);
        v = *(const float4*)(r1 + 1024); ST4(48,49,50,51, v);
        v = *(const float4*)(r1 + 1280); ST4(52,53,54,55, v);
        v = *(const float4*)(r1 + 1536); ST4(56,57,58,59, v);
        v = *(const float4*)(r1 + 1792); ST4(60,61,62,63, v);
        v = *(const float4*)(r2 +    0); ST4(64,65,66,67, v);
        v = *(const float4*)(r2 +  256); ST4(68,69,70,71, v);
        v = *(const float4*)(r2 +  512); ST4(72,73,74,75, v);
        v = *(const float4*)(r2 +  768); ST4(76,77,78,79, v);
        v = *(const float4*)(r2 + 1024); ST4(80,81,82,83, v);
        v = *(const float4*)(r2 + 1280); ST4(84,85,86,87, v);
        v = *(const float4*)(r2 + 1536); ST4(88,89,90,91, v);
        v = *(const float4*)(r2 + 1792); ST4(92,93,94,95, v);
        v = *(const float4*)(r3 +    0); ST4(96,97,98,99, v);
        v = *(const float4*)(r3 +  256); ST4(100,101,102,103, v);
        v = *(const float4*)(r3 +  512); ST4(104,105,106,107, v);
        v = *(const float4*)(r3 +  768); ST4(108,109,110,111, v);
        v = *(const float4*)(r3 + 1024); ST4(112,113,114,115, v);
        v = *(const float4*)(r3 + 1280); ST4(116,117,118,119, v);
        v = *(const float4*)(r3 + 1536); ST4(120,121,122,123, v);
        v = *(const float4*)(r3 + 1792); ST4(124,125,126,127, v);
    }
    const float4 ww = *(const float4*)(Wout + (size_t)cu * HID + tid * 4);
    const float bout_cu = boutv[cu];
    const unsigned zaddr = (unsigned)(size_t)&z_lds[4 * ln];   // LDS byte offset

    float c = c0[j];                      // meaningful at lane 63 (the owner)

    // publish h_0 (tag 1): coalesced 64B from lanes 0..7 of wave 0
    if (tid < 8) {
        const int jm = cu * 8 + tid;
        __hip_atomic_store(&hbuf[jm], packpair(h0[jm], 1u),
                           __ATOMIC_RELAXED, __HIP_MEMORY_SCOPE_AGENT);
    }

    int budget = 1 << 22;                 // loud-fail spin budget
    float hv0 = 0.f, hv1 = 0.f, hv2 = 0.f, hv3 = 0.f;
    int ch = seq[0];

    #pragma unroll 1
    for (int t = 0; t < SEQ; ++t) {
        // x-contribution for this step (broadcast float4; issue early)
        int chv = ch;
        asm volatile("" : "+v"(chv));
        const float4 p4 = *(const float4*)(Ptab + ((size_t)(unsigned)chv << 13) + (j << 2));
        if (t + 1 < SEQ) ch = seq[t + 1];

        // poll own 4 pairs of h_t (tag t+1) via 2x16B bypass loads
        {
            const unsigned long long* p = hbuf + (size_t)(t & 1) * HID + tid * 4;
            const unsigned want = (unsigned)(t + 1);
            u32x4 q0, q1;
            while (true) {
                asm volatile(
                    "global_load_dwordx4 %0, %2, off sc0 sc1\n\t"
                    "global_load_dwordx4 %1, %3, off sc0 sc1\n\t"
                    "s_waitcnt vmcnt(0)"
                    : "=&v"(q0), "=&v"(q1)
                    : "v"(p), "v"(p + 2)
                    : "memory");
                if (q0.y == want && q0.w == want && q1.y == want && q1.w == want) break;
                if (--budget < 0) break;
                __builtin_amdgcn_s_sleep(1);
            }
            hv0 = __uint_as_float(q0.x);
            hv1 = __uint_as_float(q0.z);
            hv2 = __uint_as_float(q1.x);
            hv3 = __uint_as_float(q1.z);
        }
        *(float4*)&z_lds[tid * 4] = make_float4(hv0, hv1, hv2, hv3);
        __syncthreads();

        // 4 gate dots over h (K=2048): opaque asm, weights from AGPRs (proven R6)
        float ac0 = 0.f, ac1 = 0.f, ac2 = 0.f, ac3 = 0.f;
        asm volatile(
            "s_waitcnt lgkmcnt(0)\n\t"
            "ds_read_b128 v[60:63], %[za] offset:0\n\t"
            "ds_read_b128 v[64:67], %[za] offset:1024\n\t"
            "s_waitcnt lgkmcnt(1)\n\t"
            DOT16(0,1,2,3, 32,33,34,35, 64,65,66,67, 96,97,98,99, "v60","v61","v62","v63")
            "ds_read_b128 v[60:63], %[za] offset:2048\n\t"
            "s_waitcnt lgkmcnt(1)\n\t"
            DOT16(4,5,6,7, 36,37,38,39, 68,69,70,71, 100,101,102,103, "v64","v65","v66","v67")
            "ds_read_b128 v[64:67], %[za] offset:3072\n\t"
            "s_waitcnt lgkmcnt(1)\n\t"
            DOT16(8,9,10,11, 40,41,42,43, 72,73,74,75, 104,105,106,107, "v60","v61","v62","v63")
            "ds_read_b128 v[60:63], %[za] offset:4096\n\t"
            "s_waitcnt lgkmcnt(1)\n\t"
            DOT16(12,13,14,15, 44,45,46,47, 76,77,78,79, 108,109,110,111, "v64","v65","v66","v67")
            "ds_read_b128 v[64:67], %[za] offset:5120\n\t"
            "s_waitcnt lgkmcnt(1)\n\t"
            DOT16(16,17,18,19, 48,49,50,51, 80,81,82,83, 112,113,114,115, "v60","v61","v62","v63")
            "ds_read_b128 v[60:63], %[za] offset:6144\n\t"
            "s_waitcnt lgkmcnt(1)\n\t"
            DOT16(20,21,22,23, 52,53,54,55, 84,85,86,87, 116,117,118,119, "v64","v65","v66","v67")
            "ds_read_b128 v[64:67], %[za] offset:7168\n\t"
            "s_waitcnt lgkmcnt(1)\n\t"
            DOT16(24,25,26,27, 56,57,58,59, 88,89,90,91, 120,121,122,123, "v60","v61","v62","v63")
            "s_waitcnt lgkmcnt(0)\n\t"
            DOT16(28,29,30,31, 60,61,62,63, 92,93,94,95, 124,125,126,127, "v64","v65","v66","v67")
            : "+v"(ac0), "+v"(ac1), "+v"(ac2), "+v"(ac3)
            : [za] "v"(zaddr)
            : ACLOB, VCLOB, "memory");

        // Wout partial for pred_{t-1} = Wout @ h_t
        float aw = fmaf(ww.x, hv0, fmaf(ww.y, hv1, fmaf(ww.z, hv2, ww.w * hv3)));

        ac0 = wave_sum(ac0); ac1 = wave_sum(ac1);
        ac2 = wave_sum(ac2); ac3 = wave_sum(ac3);
        aw  = wave_sum(aw);

        if (ln == 63) {
            const float gf = 1.f / (1.f + __expf(-(ac0 + p4.x)));
            const float gi = 1.f / (1.f + __expf(-(ac1 + p4.y)));
            const float go = 1.f / (1.f + __expf(-(ac2 + p4.z)));
            const float ct = tanhf(ac3 + p4.w);
            c = fmaf(gf, c, gi * ct);
            hpub[wv] = go * tanhf(c);
            wred[wv] = aw;
        }
        __syncthreads();
        // coalesced publish: lanes 0..7 of wave 0 -> one 64B transaction
        if (tid < 8) {
            __hip_atomic_store(&hbuf[(size_t)((t + 1) & 1) * HID + cu * 8 + tid],
                               packpair(hpub[tid], (unsigned)(t + 2)),
                               __ATOMIC_RELAXED, __HIP_MEMORY_SCOPE_AGENT);
        }
        if (tid == NTH - 1 && t >= 1) {
            float s = bout_cu;
            #pragma unroll
            for (int q = 0; q < 8; ++q) s += wred[q];
            out[(size_t)(t - 1) * NCH + cu] = s;
        }
    }

    // ---- epilogue: pred_{SEQ-1} = Wout @ h_SEQ (tag SEQ+1, slot 0) ----
    {
        const unsigned long long* p = hbuf + (size_t)(SEQ & 1) * HID + tid * 4;
        const unsigned want = (unsigned)(SEQ + 1);
        u32x4 q0, q1;
        while (true) {
            asm volatile(
                "global_load_dwordx4 %0, %2, off sc0 sc1\n\t"
                "global_load_dwordx4 %1, %3, off sc0 sc1\n\t"
                "s_waitcnt vmcnt(0)"
                : "=&v"(q0), "=&v"(q1)
                : "v"(p), "v"(p + 2)
                : "memory");
            if (q0.y == want && q0.w == want && q1.y == want && q1.w == want) break;
            if (--budget < 0) break;
            __builtin_amdgcn_s_sleep(1);
        }
        hv0 = __uint_as_float(q0.x);
        hv1 = __uint_as_float(q0.z);
        hv2 = __uint_as_float(q1.x);
        hv3 = __uint_as_float(q1.z);

        float aw = fmaf(ww.x, hv0, fmaf(ww.y, hv1, fmaf(ww.z, hv2, ww.w * hv3)));
        aw = wave_sum(aw);
        if (ln == 63) wred[wv] = aw;
        __syncthreads();
        if (tid == NTH - 1) {
            float s = bout_cu;
            #pragma unroll
            for (int q = 0; q < 8; ++q) s += wred[q];
            out[(size_t)(SEQ - 1) * NCH + cu] = s;
        }
        if (cu == 0) {
            *(float4*)&out[(size_t)SEQ * NCH + tid * 4] =
                make_float4(hv0, hv1, hv2, hv3);
        }
        if (ln == 63) out[(size_t)SEQ * NCH + HID + j] = c;
    }
}

extern "C" void kernel_launch(void* const* d_in, const int* in_sizes, int n_in,
                              void* d_out, int out_size, void* d_ws, size_t ws_size,
                              hipStream_t stream)
{
    const int*   seq  = (const int*)  d_in[0];
    const float* h0   = (const float*)d_in[1];
    const float* c0   = (const float*)d_in[2];
    const float* emb  = (const float*)d_in[3];
    const float* Wf   = (const float*)d_in[4];
    const float* bf_  = (const float*)d_in[5];
    const float* Wi   = (const float*)d_in[6];
    const float* bi_  = (const float*)d_in[7];
    const float* Wo   = (const float*)d_in[8];
    const float* bo_  = (const float*)d_in[9];
    const float* Wc   = (const float*)d_in[10];
    const float* bc_  = (const float*)d_in[11];
    const float* Wout = (const float*)d_in[12];
    const float* bout = (const float*)d_in[13];
    float* out = (float*)d_out;

    unsigned long long* hbuf = (unsigned long long*)d_ws;        // 32 KB
    float* Ptab = (float*)((char*)d_ws + 2 * HID * sizeof(unsigned long long)); // 8 MB

    build_ptab<<<dim3(NROW), dim3(256), 0, stream>>>(
        emb, Wf, Wi, Wo, Wc, bf_, bi_, bo_, bc_, Ptab);

    void* args[] = { (void*)&seq, (void*)&h0, (void*)&c0,
                     (void*)&Wf, (void*)&Wi, (void*)&Wo, (void*)&Wc,
                     (void*)&Wout, (void*)&bout, (void*)&Ptab,
                     (void*)&out, (void*)&hbuf };

    hipError_t e = hipLaunchCooperativeKernel((void*)lstm_persistent,
                                              dim3(NBLK), dim3(NTH),
                                              args, 0, stream);
    if (e != hipSuccess) {
        lstm_persistent<<<dim3(NBLK), dim3(NTH), 0, stream>>>(
            seq, h0, c0, Wf, Wi, Wo, Wc, Wout, bout, Ptab, out, hbuf);
    }
}